// Round 9
// baseline (282.786 us; speedup 1.0000x reference)
//
#include <hip/hip_runtime.h>
#include <hip/hip_bf16.h>

// CrossModalMDTA on gfx950 — round 9.
// Round-8 structure; GEMMs widened to BN=256 (1KB read / 512B write bursts
// per 64KB-strided row) with 8-wave blocks, split-K=64 double-buffer.
// proj_gemm blocks swizzled so q/k/v blocks sharing the same B-columns land
// on the same XCD (f_sar second read becomes an L2 hit).

typedef __attribute__((ext_vector_type(8))) short short8;   // 8 x bf16
typedef __attribute__((ext_vector_type(4))) float f32x4;    // MFMA accum

static __device__ __forceinline__ float b2f(unsigned short u) {
    return __uint_as_float(((unsigned)u) << 16);
}
static __device__ __forceinline__ unsigned short f2b(float f) {
    unsigned u = __float_as_uint(f);
    u += 0x7FFFu + ((u >> 16) & 1u);          // RNE
    return (unsigned short)(u >> 16);
}
static __device__ __forceinline__ unsigned short f2bh(float f) {
    union { __hip_bfloat16 h; unsigned short u; } cv;
    cv.h = __float2bfloat16(f);
    return cv.u;
}

__global__ void cvt_f2b_kernel(const float* __restrict__ src,
                               unsigned short* __restrict__ dst, int n) {
    int i = blockIdx.x * blockDim.x + threadIdx.x;
    if (i < n) dst[i] = f2b(src[i]);
}

// ---------------------------------------------------------------------------
// GEMM body: C[m,n] = sum_k A[m,k]*B[k,n], K=192, N=16384, M=192.
// Block = 8 waves (512 thr), tile 192m x 256n. Wave (wm=wave&3, wn=wave>>2)
// owns rows 48*wm..+47, cols wn*128..+127 (3 mt x 8 nt). K split into 3
// stages of 64, double-buffered; next-stage loads issue before MFMA sweep.
// ---------------------------------------------------------------------------
template<typename Bty, typename Oty>
static __device__ __forceinline__ void gemm_body256(
    const unsigned short* __restrict__ A,   // bf16 [192 x 192]
    const Bty* __restrict__ B,              // [192 x N] fp32 or bf16
    Oty* __restrict__ C,                    // [192 x N] bf16(ushort) or fp32
    long n0)
{
    constexpr long N = 16384;
    constexpr int K = 192;
    const int tid  = threadIdx.x;
    const int wave = tid >> 6;
    const int wm   = wave & 3;
    const int wn   = wave >> 2;
    const int lane = tid & 63;
    const int l15  = lane & 15;
    const int g    = lane >> 4;

    __shared__ unsigned short Bs[2][256][72];   // 73.7 KB, rows 144B

    const int nc = tid & 255;       // n column
    const int kb = tid >> 8;        // 0..1 (k-chunk parity)

    float fv[4][8];
    unsigned short sv[4][8];

    auto load_regs = [&](int s) {
#pragma unroll
        for (int i = 0; i < 4; ++i) {
            const int kc = kb + 2 * i;              // local k-chunk 0..7
            const Bty* bp = B + (long)(s * 64 + kc * 8) * N + n0 + nc;
#pragma unroll
            for (int j = 0; j < 8; ++j) {
                if constexpr (sizeof(Bty) == 4) fv[i][j] = (float)bp[j * N];
                else                            sv[i][j] = bp[j * N];
            }
        }
    };
    auto write_lds = [&](int buf) {
#pragma unroll
        for (int i = 0; i < 4; ++i) {
            const int kc = kb + 2 * i;
            unsigned w[4];
#pragma unroll
            for (int t = 0; t < 4; ++t) {
                if constexpr (sizeof(Bty) == 4)
                    w[t] = (unsigned)f2bh(fv[i][2*t]) | ((unsigned)f2bh(fv[i][2*t+1]) << 16);
                else
                    w[t] = (unsigned)sv[i][2*t] | ((unsigned)sv[i][2*t+1] << 16);
            }
            uint4 pk = {w[0], w[1], w[2], w[3]};
            *reinterpret_cast<uint4*>(&Bs[buf][nc][kc * 8]) = pk;
        }
    };

    f32x4 acc[3][8];
#pragma unroll
    for (int i = 0; i < 3; ++i)
#pragma unroll
        for (int j = 0; j < 8; ++j) acc[i][j] = {0.f, 0.f, 0.f, 0.f};

    load_regs(0);
    write_lds(0);
    __syncthreads();

#pragma unroll
    for (int s = 0; s < 3; ++s) {
        const int buf = s & 1;
        if (s < 2) load_regs(s + 1);        // overlap with MFMA below
#pragma unroll
        for (int s32 = 0; s32 < 2; ++s32) {
            short8 af[3];
#pragma unroll
            for (int mt = 0; mt < 3; ++mt)
                af[mt] = *reinterpret_cast<const short8*>(
                    A + (long)(wm * 48 + mt * 16 + l15) * K + s * 64 + s32 * 32 + g * 8);
            short8 bf[8];
#pragma unroll
            for (int nt = 0; nt < 8; ++nt)
                bf[nt] = *reinterpret_cast<const short8*>(
                    &Bs[buf][wn * 128 + nt * 16 + l15][s32 * 32 + g * 8]);
#pragma unroll
            for (int nt = 0; nt < 8; ++nt)
#pragma unroll
                for (int mt = 0; mt < 3; ++mt)
                    acc[mt][nt] = __builtin_amdgcn_mfma_f32_16x16x32_bf16(
                        af[mt], bf[nt], acc[mt][nt], 0, 0, 0);
        }
        if (s < 2) {
            write_lds(buf ^ 1);             // other buffer: safe concurrently
            __syncthreads();
        }
    }

    // epilogue: D row = (lane>>4)*4 + r, col = lane&15
#pragma unroll
    for (int mt = 0; mt < 3; ++mt) {
#pragma unroll
        for (int nt = 0; nt < 8; ++nt) {
            const int row = wm * 48 + mt * 16 + g * 4;
            const long col = n0 + wn * 128 + nt * 16 + l15;
#pragma unroll
            for (int r = 0; r < 4; ++r) {
                const float v = acc[mt][nt][r];
                if constexpr (sizeof(Oty) == 4)
                    C[(long)(row + r) * N + col] = v;
                else
                    C[(long)(row + r) * N + col] = f2b(v);
            }
        }
    }
}

// fused q + kv projection, XCD-packed: lid -> (xcd = lid&7, slot = lid>>3),
// n0i = xcd*8 + slot/3, y = slot%3  (the 3 y-groups of one n0 share an XCD).
__global__ void __launch_bounds__(512) proj_gemm(
    const unsigned short* __restrict__ wq_b,   // [192x192] bf16
    const unsigned short* __restrict__ wkv_b,  // [384x192] bf16
    const float* __restrict__ f_opt,
    const float* __restrict__ f_sar,
    unsigned short* __restrict__ q0,
    unsigned short* __restrict__ kv0,
    long q0S, long kv0S, int batch0)
{
    constexpr long N = 16384;
    const int b = batch0 + blockIdx.z;
    const int lid  = blockIdx.x;          // 0..191
    const int xcd  = lid & 7;
    const int slot = lid >> 3;            // 0..23
    const int n0i  = xcd * 8 + slot / 3;  // 0..63
    const int y    = slot - 3 * (slot / 3);
    const long n0  = (long)n0i * 256;

    if (y == 0) {
        gemm_body256<float, unsigned short>(
            wq_b, f_opt + (long)b * 192 * N, q0 + (long)b * q0S, n0);
    } else {
        gemm_body256<float, unsigned short>(
            wkv_b + (long)(y - 1) * 192 * 192,
            f_sar + (long)b * 192 * N,
            kv0 + (long)b * kv0S + (long)(y - 1) * 192 * N, n0);
    }
}

// final: out = M_b @ v
__global__ void __launch_bounds__(512) final_gemm(
    const unsigned short* __restrict__ Mmat,   // [B,192,192] bf16
    const unsigned short* __restrict__ v,      // v rows, stride vStride per b
    float* __restrict__ out, long vStride)
{
    constexpr long N = 16384;
    const int b = blockIdx.z;
    gemm_body256<unsigned short, float>(
        Mmat + (long)b * 192 * 192, v + (long)b * vStride,
        out + (long)b * 192 * N, (long)blockIdx.x * 256);
}

// ---------------------------------------------------------------------------
// depthwise 3x3 (SAME, zero pad), bf16 in/out, fp32 accum — q and kv merged.
// Halo via lane shuffles (round 8).
// ---------------------------------------------------------------------------
__global__ void __launch_bounds__(256) dw3x3_all(
    const unsigned short* __restrict__ q0,
    const unsigned short* __restrict__ kv0,
    unsigned short* __restrict__ qbuf,
    unsigned short* __restrict__ kvbuf,
    const float* __restrict__ w_qdw,        // [192][9]
    const float* __restrict__ w_kvdw,       // [384][9]
    float* __restrict__ nqPart,             // [B][192][32]
    float* __restrict__ nkPart,             // [B][192][32]
    long q0S, long kv0S, int batch0)
{
    const int b  = batch0 + blockIdx.z;
    const int t  = blockIdx.x * 256 + threadIdx.x;
    const int l16 = threadIdx.x & 15;
    const int w0 = l16 * 8;
    const int hh = (t >> 4) & 127;
    const int c_all = t >> 11;               // 0..575
    if (c_all >= 576) return;

    const unsigned short* s;
    unsigned short* d;
    const float* wp;
    if (c_all < 192) {
        s  = q0 + (long)b * q0S + ((long)c_all << 14);
        d  = qbuf + ((long)b * 192 + c_all) * 16384;
        wp = w_qdw + c_all * 9;
    } else {
        const int c = c_all - 192;
        s  = kv0 + (long)b * kv0S + ((long)c << 14);
        d  = kvbuf + ((long)b * 384 + c) * 16384;
        wp = w_kvdw + c * 9;
    }

    float wt[9];
#pragma unroll
    for (int i = 0; i < 9; ++i) wt[i] = wp[i];

    float acc[8] = {0, 0, 0, 0, 0, 0, 0, 0};
#pragma unroll
    for (int dy = 0; dy < 3; ++dy) {
        const int hy = hh + dy - 1;
        if (hy < 0 || hy > 127) continue;
        const unsigned short* row = s + hy * 128 + w0;
        float r[10];
        const short8 v = *reinterpret_cast<const short8*>(row);
#pragma unroll
        for (int i = 0; i < 8; ++i) r[i + 1] = b2f((unsigned short)v[i]);
        const float left  = __shfl_up(r[8], 1);
        const float right = __shfl_down(r[1], 1);
        r[0] = (l16 > 0)  ? left  : 0.f;
        r[9] = (l16 < 15) ? right : 0.f;
#pragma unroll
        for (int j = 0; j < 8; ++j)
            acc[j] += wt[dy*3+0]*r[j] + wt[dy*3+1]*r[j+1] + wt[dy*3+2]*r[j+2];
    }

    short8 o;
#pragma unroll
    for (int j = 0; j < 8; ++j) o[j] = (short)f2b(acc[j]);
    *reinterpret_cast<short8*>(d + hh * 128 + w0) = o;

    float* np = nullptr;
    if (c_all < 192)      np = nqPart + ((long)b * 192 + c_all) * 32;
    else if (c_all < 384) np = nkPart + ((long)b * 192 + (c_all - 192)) * 32;
    if (np) {
        float ssq = 0.f;
#pragma unroll
        for (int j = 0; j < 8; ++j) ssq += acc[j] * acc[j];
#pragma unroll
        for (int ofs = 1; ofs < 64; ofs <<= 1) ssq += __shfl_xor(ssq, ofs);
        if ((threadIdx.x & 63) == 0) np[(t & 2047) >> 6] = ssq;
    }
}

// ---------------------------------------------------------------------------
// Gram: G[d,e] = sum_n q[d,n]*k[e,n] per (b,h), N chunked into 16 x 1024.
// ---------------------------------------------------------------------------
__global__ void __launch_bounds__(256) gram_kernel(
    const unsigned short* __restrict__ q,    // [B,192,N] bf16
    const unsigned short* __restrict__ kv,   // [B,384,N] bf16 (k = first 192)
    float* __restrict__ Gpart)               // [B,4,16,2304]
{
    constexpr long N = 16384;
    const int chunk = blockIdx.x, h = blockIdx.y, b = blockIdx.z;
    const int tid = threadIdx.x;
    const int wave = tid >> 6, lane = tid & 63;
    const int l15 = lane & 15, g = lane >> 4;
    const unsigned short* qp = q  + ((long)b * 192 + h * 48) * N;
    const unsigned short* kp = kv + ((long)b * 384 + h * 48) * N;
    const int nbase = chunk * 1024 + wave * 256;

    f32x4 acc[3][3];
#pragma unroll
    for (int i = 0; i < 3; ++i)
#pragma unroll
        for (int j = 0; j < 3; ++j) acc[i][j] = {0.f, 0.f, 0.f, 0.f};

    for (int s = 0; s < 8; ++s) {
        const long n0 = nbase + s * 32 + g * 8;
        short8 af[3], bf[3];
#pragma unroll
        for (int mt = 0; mt < 3; ++mt)
            af[mt] = *reinterpret_cast<const short8*>(qp + (long)(mt*16 + l15) * N + n0);
#pragma unroll
        for (int nt = 0; nt < 3; ++nt)
            bf[nt] = *reinterpret_cast<const short8*>(kp + (long)(nt*16 + l15) * N + n0);
#pragma unroll
        for (int mt = 0; mt < 3; ++mt)
#pragma unroll
            for (int nt = 0; nt < 3; ++nt)
                acc[mt][nt] = __builtin_amdgcn_mfma_f32_16x16x32_bf16(
                    af[mt], bf[nt], acc[mt][nt], 0, 0, 0);
    }

    __shared__ float Gt[4][2304];
#pragma unroll
    for (int mt = 0; mt < 3; ++mt)
#pragma unroll
        for (int nt = 0; nt < 3; ++nt)
#pragma unroll
            for (int r = 0; r < 4; ++r)
                Gt[wave][(mt*16 + g*4 + r) * 48 + nt*16 + l15] = acc[mt][nt][r];
    __syncthreads();

    float* gout = Gpart + (((long)(b * 4 + h)) * 16 + chunk) * 2304;
    for (int i = tid; i < 2304; i += 256)
        gout[i] = Gt[0][i] + Gt[1][i] + Gt[2][i] + Gt[3][i];
}

// ---------------------------------------------------------------------------
// Per (b,h): reduce partials, softmax(G/(nq*nk)*T), fold w_out:
// M[c, 48h+e] = sum_d w_out[c, 48h+d] * attn[d,e]
// ---------------------------------------------------------------------------
__global__ void __launch_bounds__(256) attn_m_kernel(
    const float* __restrict__ Gpart,        // [B,4,16,2304]
    const float* __restrict__ nqPart,       // [B,192,32]
    const float* __restrict__ nkPart,       // [B,192,32]
    const float* __restrict__ w_out,        // [192,192] fp32
    const float* __restrict__ temperature,  // [4]
    unsigned short* __restrict__ Mmat)      // [B,192,192] bf16
{
    const int blk = blockIdx.x;
    const int b = blk >> 2, h = blk & 3;
    const int tid = threadIdx.x;
    __shared__ float G[2304];
    __shared__ float At[2304];
    __shared__ float nqv[48], nkv[48];

    const long base = ((long)(b * 4 + h)) * 16;
    for (int i = tid; i < 2304; i += 256) {
        float s = 0.f;
        for (int c = 0; c < 16; ++c) s += Gpart[(base + c) * 2304 + i];
        G[i] = s;
    }
    if (tid < 96) {
        const int isK = tid >= 48;
        const int d = tid - 48 * isK;
        const float* p = (isK ? nkPart : nqPart) + ((long)b * 192 + h * 48 + d) * 32;
        float s = 0.f;
        for (int i = 0; i < 32; ++i) s += p[i];
        const float nrm = fmaxf(sqrtf(s), 1e-12f);
        if (isK) nkv[d] = nrm; else nqv[d] = nrm;
    }
    __syncthreads();

    const float T = temperature[h];
    if (tid < 48) {
        const int d = tid;
        const float scale = T / nqv[d];
        float m = -1e30f;
        for (int e = 0; e < 48; ++e) {
            const float sv = G[d * 48 + e] * scale / nkv[e];
            At[d * 48 + e] = sv;
            m = fmaxf(m, sv);
        }
        float sum = 0.f;
        for (int e = 0; e < 48; ++e) {
            const float ex = expf(At[d * 48 + e] - m);
            At[d * 48 + e] = ex;
            sum += ex;
        }
        const float inv = 1.f / sum;
        for (int e = 0; e < 48; ++e) At[d * 48 + e] *= inv;
    }
    __syncthreads();

    for (int i = tid; i < 192 * 48; i += 256) {
        const int c = i / 48, e = i - (i / 48) * 48;
        const float* wrow = w_out + (long)c * 192 + h * 48;
        float s = 0.f;
        for (int d = 0; d < 48; ++d) s += wrow[d] * At[d * 48 + e];
        Mmat[((long)b * 192 + c) * 192 + h * 48 + e] = f2b(s);
    }
}

// ---------------------------------------------------------------------------
extern "C" void kernel_launch(void* const* d_in, const int* in_sizes, int n_in,
                              void* d_out, int out_size, void* d_ws, size_t ws_size,
                              hipStream_t stream)
{
    const float* f_opt  = (const float*)d_in[0];
    const float* f_sar  = (const float*)d_in[1];
    const float* w_q    = (const float*)d_in[2];
    const float* w_qdw  = (const float*)d_in[3];
    const float* w_kv   = (const float*)d_in[4];
    const float* w_kvdw = (const float*)d_in[5];
    const float* w_out  = (const float*)d_in[6];
    const float* temper = (const float*)d_in[7];
    float* out = (float*)d_out;

    const long N = 16384;
    char* ws = (char*)d_ws;
    size_t off = 0;
    auto alloc = [&](size_t bytes) -> void* {
        void* p = ws + off;
        off = (off + bytes + 255) & ~(size_t)255;
        return p;
    };

    unsigned short* wq_b  = (unsigned short*)alloc((size_t)192 * 192 * 2);
    unsigned short* wkv_b = (unsigned short*)alloc((size_t)384 * 192 * 2);
    unsigned short* Mmat  = (unsigned short*)alloc((size_t)8 * 192 * 192 * 2);
    float* Gpart  = (float*)alloc((size_t)8 * 4 * 16 * 2304 * 4);
    float* nqPart = (float*)alloc((size_t)8 * 192 * 32 * 4);
    float* nkPart = (float*)alloc((size_t)8 * 192 * 32 * 4);
    unsigned short* qbuf  = (unsigned short*)alloc((size_t)8 * 192 * N * 2);
    unsigned short* kvbuf = (unsigned short*)alloc((size_t)8 * 384 * N * 2);

    const size_t fullNeed = off + ((size_t)8 * 192 * N * 2 + 256)
                                + ((size_t)8 * 384 * N * 2 + 256);
    const bool full = (ws_size >= fullNeed);

    unsigned short *q0, *kv0;
    long q0S, kv0S; int nz;
    if (full) {
        q0  = (unsigned short*)alloc((size_t)8 * 192 * N * 2);
        kv0 = (unsigned short*)alloc((size_t)8 * 384 * N * 2);
        q0S = 192 * N; kv0S = 384 * N; nz = 8;
    } else {
        q0  = (unsigned short*)alloc((size_t)192 * N * 2);
        kv0 = (unsigned short*)alloc((size_t)384 * N * 2);
        q0S = 0; kv0S = 0; nz = 1;
    }

    cvt_f2b_kernel<<<dim3((192*192 + 255) / 256), 256, 0, stream>>>(w_q,  wq_b,  192*192);
    cvt_f2b_kernel<<<dim3((384*192 + 255) / 256), 256, 0, stream>>>(w_kv, wkv_b, 384*192);

    const int iters = full ? 1 : 8;
    for (int it = 0; it < iters; ++it) {
        const int b0 = full ? 0 : it;
        proj_gemm<<<dim3(192, 1, nz), 512, 0, stream>>>(
            wq_b, wkv_b, f_opt, f_sar, q0, kv0, q0S, kv0S, b0);
        dw3x3_all<<<dim3(4608, 1, nz), 256, 0, stream>>>(
            q0, kv0, qbuf, kvbuf, w_qdw, w_kvdw, nqPart, nkPart, q0S, kv0S, b0);
    }

    gram_kernel<<<dim3(16, 4, 8), 256, 0, stream>>>(qbuf, kvbuf, Gpart);
    attn_m_kernel<<<dim3(32), 256, 0, stream>>>(Gpart, nqPart, nkPart, w_out, temper, Mmat);

    // out = M_b @ v  (v = channels 192..383 of kv)
    final_gemm<<<dim3(64, 1, 8), 512, 0, stream>>>(
        Mmat, kvbuf + 192 * N, out, 384 * N);
}